// Round 3
// baseline (381.219 us; speedup 1.0000x reference)
//
#include <hip/hip_runtime.h>
#include <cstdint>

#define BB 256
#define DD 512
#define CC 345
#define NBANK 50000
#define NPAD 50048          // 391 * 128
#define KNEI 5
#define ALPHAC 1.0f
#define EPSN 1e-12f

#define NTILES 391          // ceil(50000/128)
#define CAND (NTILES * 6)   // 2346 candidates per row

typedef short short8 __attribute__((ext_vector_type(8)));
typedef float f32x4 __attribute__((ext_vector_type(4)));

__device__ inline uint32_t f2bf1(float x) {
    union { float f; uint32_t u; } v; v.f = x;
    return (v.u + 0x7FFFu + ((v.u >> 16) & 1u)) >> 16;
}
__device__ inline uint32_t pack2(float a, float b) {
    return f2bf1(a) | (f2bf1(b) << 16);
}
__device__ inline bool better(float v1, int i1, float v2, int i2) {
    return (v1 > v2) || (v1 == v2 && i1 < i2);
}
// async 16B/lane global->LDS: gptr per-lane, lptr wave-uniform base
__device__ inline void async16(const void* g, void* l) {
    __builtin_amdgcn_global_load_lds(
        (const __attribute__((address_space(1))) unsigned int*)g,
        (__attribute__((address_space(3))) unsigned int*)l, 16, 0, 0);
}

// tiled+swizzled element offset: tile t128 (128 rows x 64 cols), row r, chunk ch (8 el), sub s
__device__ inline size_t sw_off(int tile, int r, int ch) {
    return (size_t)tile * 8192 + r * 64 + ((ch ^ (r & 7)) * 8);
}

// Kernel 1: repl[j] = -1
__global__ void repl_init_kernel(int* __restrict__ repl) {
    int idx = blockIdx.x * 256 + threadIdx.x;
    if (idx < NPAD) repl[idx] = -1;
}

// Kernel 2: zero out; last-write-wins scatter repl[trg[b]] = b
__global__ void winner_kernel(const int* __restrict__ trg, int* __restrict__ repl,
                              float* __restrict__ out) {
    int t = threadIdx.x;
    if (t == 0) out[0] = 0.f;
    int mv = trg[t];
    int w = 1;
    for (int b2 = t + 1; b2 < BB; b2++)
        if (trg[b2] == mv) w = 0;
    if (w) repl[mv] = t;
}

// Kernel 3: row L2-normalize features -> plain bf16 fnb + tiled/swizzled fnb2
__global__ void norm_kernel(const float* __restrict__ feat,
                            unsigned short* __restrict__ fnb,
                            unsigned short* __restrict__ fnb2) {
    int b = blockIdx.x, t = threadIdx.x;
    float x0 = feat[b * DD + t];
    float x1 = feat[b * DD + t + 256];
    __shared__ float red[256];
    red[t] = x0 * x0 + x1 * x1;
    __syncthreads();
    for (int s = 128; s > 0; s >>= 1) {
        if (t < s) red[t] += red[t + s];
        __syncthreads();
    }
    float inv = 1.0f / fmaxf(sqrtf(red[0]), EPSN);
    if (t < 64) {
        const f32x4* src = (const f32x4*)(feat + b * DD + t * 8);
        f32x4 f0 = src[0], f1 = src[1];
        uint4 u = make_uint4(pack2(f0[0] * inv, f0[1] * inv),
                             pack2(f0[2] * inv, f0[3] * inv),
                             pack2(f1[0] * inv, f1[1] * inv),
                             pack2(f1[2] * inv, f1[3] * inv));
        *(uint4*)(fnb + b * DD + t * 8) = u;
        int mtile = b >> 7, r = b & 127, kt = t >> 3, ch = t & 7;
        *(uint4*)(fnb2 + sw_off(mtile * 8 + kt, r, ch)) = u;
    }
}

// Kernel 4: row softmax of predictions
__global__ void softmax_kernel(const float* __restrict__ pred, float* __restrict__ p) {
    int b = blockIdx.x, t = threadIdx.x;
    float x0 = (t < CC) ? pred[b * CC + t] : -3.0e38f;
    float x1 = (t + 256 < CC) ? pred[b * CC + t + 256] : -3.0e38f;
    __shared__ float red[256];
    red[t] = fmaxf(x0, x1);
    __syncthreads();
    for (int s = 128; s > 0; s >>= 1) {
        if (t < s) red[t] = fmaxf(red[t], red[t + s]);
        __syncthreads();
    }
    float M = red[0];
    __syncthreads();
    float e0 = (t < CC) ? expf(x0 - M) : 0.f;
    float e1 = (t + 256 < CC) ? expf(x1 - M) : 0.f;
    red[t] = e0 + e1;
    __syncthreads();
    for (int s = 128; s > 0; s >>= 1) {
        if (t < s) red[t] += red[t + s];
        __syncthreads();
    }
    float inv = 1.0f / red[0];
    if (t < CC) p[b * CC + t] = e0 * inv;
    if (t + 256 < CC) p[b * CC + t + 256] = e1 * inv;
}

// Kernel 5: bank f32 -> bf16, repl-patched, tiled+swizzled; pad rows zeroed
__global__ void convert_kernel(const float* __restrict__ bank,
                               const unsigned short* __restrict__ fnb,
                               const int* __restrict__ repl,
                               unsigned short* __restrict__ bankb) {
    int tid = blockIdx.x * 256 + threadIdx.x;   // one thread per 8-elem chunk
    int j = tid >> 6, c = tid & 63;
    int kt = c >> 3, ch = c & 7;
    int r = j & 127, nt = j >> 7;
    uint4 val = make_uint4(0, 0, 0, 0);
    if (j < NBANK) {
        int rp = repl[j];
        int k = kt * 64 + ch * 8;
        if (rp >= 0) {
            val = *(const uint4*)(fnb + rp * DD + k);
        } else {
            const f32x4* s = (const f32x4*)(bank + (size_t)j * DD + k);
            f32x4 f0 = s[0], f1 = s[1];
            val = make_uint4(pack2(f0[0], f0[1]), pack2(f0[2], f0[3]),
                             pack2(f1[0], f1[1]), pack2(f1[2], f1[3]));
        }
    }
    *(uint4*)(bankb + sw_off(nt * 8 + kt, r, ch)) = val;
}

// Kernel 6: 128x128x512 bf16 MFMA GEMM (m97-style async staging) + fused top-6
__global__ __launch_bounds__(256) void gemm_topk_kernel(
        const unsigned short* __restrict__ fnb2, const unsigned short* __restrict__ bankb,
        float* __restrict__ cv, int* __restrict__ ci) {
    __shared__ __align__(16) char smem[33280];
    unsigned short* As = (unsigned short*)smem;            // [128][64] 16 KB
    unsigned short* Bs = (unsigned short*)(smem + 16384);  // [128][64] 16 KB
    float* Ep = (float*)smem;                              // [64][130] 33280 B

    int t = threadIdx.x;
    int ntb = blockIdx.x >> 1, mtile = blockIdx.x & 1;
    int w = t >> 6, lane = t & 63, quad = lane >> 4, l16 = lane & 15;
    int wm = w >> 1, wn = w & 1;

    f32x4 acc[4][4];
#pragma unroll
    for (int mt = 0; mt < 4; mt++)
#pragma unroll
        for (int nt = 0; nt < 4; nt++)
            acc[mt][nt] = (f32x4){0.f, 0.f, 0.f, 0.f};

    const char* Ag = (const char*)fnb2 + (size_t)mtile * 8 * 16384;
    const char* Bg = (const char*)bankb + (size_t)ntb * 8 * 16384;

    for (int kt = 0; kt < 8; kt++) {
        size_t tb = (size_t)kt * 16384;
        int co = w * 4096 + lane * 16;
#pragma unroll
        for (int u = 0; u < 4; u++)
            async16(Ag + tb + co + u * 1024, smem + w * 4096 + u * 1024);
#pragma unroll
        for (int u = 0; u < 4; u++)
            async16(Bg + tb + co + u * 1024, smem + 16384 + w * 4096 + u * 1024);
        __syncthreads();
#pragma unroll
        for (int ks = 0; ks < 2; ks++) {
            int sw = ((ks * 4 + quad) ^ (l16 & 7)) * 8;
            short8 af[4], bf[4];
#pragma unroll
            for (int mt = 0; mt < 4; mt++)
                af[mt] = *(const short8*)(As + (wm * 64 + mt * 16 + l16) * 64 + sw);
#pragma unroll
            for (int nt = 0; nt < 4; nt++)
                bf[nt] = *(const short8*)(Bs + (wn * 64 + nt * 16 + l16) * 64 + sw);
#pragma unroll
            for (int mt = 0; mt < 4; mt++)
#pragma unroll
                for (int nt = 0; nt < 4; nt++)
                    acc[mt][nt] = __builtin_amdgcn_mfma_f32_16x16x32_bf16(
                        af[mt], bf[nt], acc[mt][nt], 0, 0, 0);
        }
        __syncthreads();
    }

    // Fused epilogue: per 64-row chunk, transpose through Ep, scan 128 cols
    int j0 = ntb * 128;
#pragma unroll
    for (int h = 0; h < 2; h++) {
        if (wm == h) {
#pragma unroll
            for (int mt = 0; mt < 4; mt++)
#pragma unroll
                for (int nt = 0; nt < 4; nt++)
#pragma unroll
                    for (int r2 = 0; r2 < 4; r2++)
                        Ep[(mt * 16 + quad * 4 + r2) * 130 + wn * 64 + nt * 16 + l16] =
                            acc[mt][nt][r2];
        }
        __syncthreads();
        if (t < 128) {
            int rowl = t >> 1;
            int c0 = (t & 1) * 64;
            float lv[6]; int li[6];
#pragma unroll
            for (int r = 0; r < 6; r++) { lv[r] = -3.4e38f; li[r] = 0x7FFFFFFF; }
            for (int c = 0; c < 64; c++) {
                int j = j0 + c0 + c;
                float v = Ep[rowl * 130 + c0 + c];
                if (j < NBANK && better(v, j, lv[5], li[5])) {
                    int q = 5;
                    while (q > 0 && better(v, j, lv[q - 1], li[q - 1])) {
                        lv[q] = lv[q - 1]; li[q] = li[q - 1]; q--;
                    }
                    lv[q] = v; li[q] = j;
                }
            }
            float bv[6]; int bi[6];
#pragma unroll
            for (int r = 0; r < 6; r++) {
                bv[r] = __shfl_xor(lv[r], 1, 64);
                bi[r] = __shfl_xor(li[r], 1, 64);
            }
            if ((t & 1) == 0) {
                float rv[6]; int ri[6];
                int x = 0, y = 0;
#pragma unroll
                for (int o = 0; o < 6; o++) {
                    if (better(lv[x], li[x], bv[y], bi[y])) { rv[o] = lv[x]; ri[o] = li[x]; x++; }
                    else                                    { rv[o] = bv[y]; ri[o] = bi[y]; y++; }
                }
                int i = mtile * 128 + h * 64 + rowl;
                size_t base = (size_t)i * CAND + (size_t)ntb * 6;
#pragma unroll
                for (int r = 0; r < 6; r++) { cv[base + r] = rv[r]; ci[base + r] = ri[r]; }
            }
        }
        __syncthreads();
    }
}

// Kernel 7: merge per-tile candidates -> global top-6, keep ranks 1..5
__global__ void merge_kernel(const float* __restrict__ cv, const int* __restrict__ ci,
                             int* __restrict__ nidx) {
    int i = blockIdx.x, t = threadIdx.x;
    const float* rv = cv + (size_t)i * CAND;
    const int* ri = ci + (size_t)i * CAND;
    float lv[6]; int li[6];
#pragma unroll
    for (int r = 0; r < 6; r++) { lv[r] = -3.4e38f; li[r] = 0x7FFFFFFF; }
    for (int q = t; q < CAND; q += 256) {
        float v = rv[q]; int j = ri[q];
        if (better(v, j, lv[5], li[5])) {
            int s = 5;
            while (s > 0 && better(v, j, lv[s - 1], li[s - 1])) {
                lv[s] = lv[s - 1]; li[s] = li[s - 1]; s--;
            }
            lv[s] = v; li[s] = j;
        }
    }
    __shared__ float sv[1536];
    __shared__ int si[1536];
#pragma unroll
    for (int r = 0; r < 6; r++) { sv[t * 6 + r] = lv[r]; si[t * 6 + r] = li[r]; }
    __syncthreads();
    for (int s = 128; s > 0; s >>= 1) {
        if (t < s) {
            float av[6], bv[6], rvv[6];
            int ai[6], bi[6], rii[6];
#pragma unroll
            for (int r = 0; r < 6; r++) {
                av[r] = sv[t * 6 + r];       ai[r] = si[t * 6 + r];
                bv[r] = sv[(t + s) * 6 + r]; bi[r] = si[(t + s) * 6 + r];
            }
            int x = 0, y = 0;
#pragma unroll
            for (int o = 0; o < 6; o++) {
                if (better(av[x], ai[x], bv[y], bi[y])) { rvv[o] = av[x]; rii[o] = ai[x]; x++; }
                else                                    { rvv[o] = bv[y]; rii[o] = bi[y]; y++; }
            }
#pragma unroll
            for (int r = 0; r < 6; r++) { sv[t * 6 + r] = rvv[r]; si[t * 6 + r] = rii[r]; }
        }
        __syncthreads();
    }
    if (t == 0) {
#pragma unroll
        for (int r = 1; r < 6; r++) nidx[i * KNEI + r - 1] = si[r];
    }
}

// Kernel 8: KL term with last-wins score patch
__global__ void kl_kernel(const float* __restrict__ p, const float* __restrict__ sbank,
                          const int* __restrict__ nidx, const int* __restrict__ trg,
                          float* __restrict__ out) {
    int b = blockIdx.x, t = threadIdx.x;
    __shared__ int sj[KNEI], sb[KNEI];
    if (t < KNEI) {
        int j = nidx[b * KNEI + t];
        sj[t] = j;
        int src = -1;
        for (int b2 = 0; b2 < BB; b2++)
            if (trg[b2] == j) src = b2;
        sb[t] = src;
    }
    __syncthreads();
    float local = 0.f;
    for (int k = 0; k < KNEI; k++) {
        int j = sj[k], src = sb[k];
        const float* srow = (src >= 0) ? (p + src * CC) : (sbank + (size_t)j * CC);
        for (int c = t; c < CC; c += 256) {
            float s = srow[c];
            local += s * (logf(s) - p[b * CC + c]);
        }
    }
    __shared__ float red[256];
    red[t] = local;
    __syncthreads();
    for (int s = 128; s > 0; s >>= 1) {
        if (t < s) red[t] += red[t + s];
        __syncthreads();
    }
    if (t == 0) atomicAdd(out, red[0] * (1.0f / BB));
}

// Kernel 9: neg_pred = (||sum_b p_b||^2 - sum_b ||p_b||^2) / B
__global__ void negpred_kernel(const float* __restrict__ p, float* __restrict__ out) {
    int t = threadIdx.x;
    float colsum = 0.f, p2 = 0.f;
    if (t < CC) {
        for (int b = 0; b < BB; b++) {
            float v = p[b * CC + t];
            colsum += v;
            p2 += v * v;
        }
    }
    __shared__ float r1[512], r2[512];
    r1[t] = colsum * colsum;
    r2[t] = p2;
    __syncthreads();
    for (int s = 256; s > 0; s >>= 1) {
        if (t < s) { r1[t] += r1[t + s]; r2[t] += r2[t + s]; }
        __syncthreads();
    }
    if (t == 0) atomicAdd(out, ALPHAC * (r1[0] - r2[0]) * (1.0f / BB));
}

extern "C" void kernel_launch(void* const* d_in, const int* in_sizes, int n_in,
                              void* d_out, int out_size, void* d_ws, size_t ws_size,
                              hipStream_t stream) {
    const float* feat  = (const float*)d_in[0];
    const float* pred  = (const float*)d_in[1];
    const float* bank  = (const float*)d_in[2];
    const float* sbank = (const float*)d_in[3];
    const int*   trg   = (const int*)d_in[4];
    float* out = (float*)d_out;

    char* ws = (char*)d_ws;
    float*          cv    = (float*)ws;                        //  2,402,304 B
    int*            ci    = (int*)(ws + 2402304);              //  2,402,304 B
    unsigned short* fnb   = (unsigned short*)(ws + 4804608);   //    262,144 B
    unsigned short* fnb2  = (unsigned short*)(ws + 5066752);   //    262,144 B
    unsigned short* bankb = (unsigned short*)(ws + 5328896);   // 51,249,152 B
    float*          p     = (float*)(ws + 56578048);           //    353,280 B
    int*            repl  = (int*)(ws + 56931328);             //    200,192 B
    int*            nidx  = (int*)(ws + 57131520);             //      5,120 B

    repl_init_kernel<<<(NPAD + 255) / 256, 256, 0, stream>>>(repl);
    winner_kernel<<<1, 256, 0, stream>>>(trg, repl, out);
    norm_kernel<<<BB, 256, 0, stream>>>(feat, fnb, fnb2);
    softmax_kernel<<<BB, 256, 0, stream>>>(pred, p);
    convert_kernel<<<(NPAD * 64) / 256, 256, 0, stream>>>(bank, fnb, repl, bankb);
    gemm_topk_kernel<<<NTILES * 2, 256, 0, stream>>>(fnb2, bankb, cv, ci);
    merge_kernel<<<BB, 256, 0, stream>>>(cv, ci, nidx);
    kl_kernel<<<BB, 256, 0, stream>>>(p, sbank, nidx, trg, out);
    negpred_kernel<<<1, 512, 0, stream>>>(p, out);
}

// Round 4
// 291.999 us; speedup vs baseline: 1.3056x; 1.3056x over previous
//
#include <hip/hip_runtime.h>
#include <cstdint>

#define BB 256
#define DD 512
#define CC 345
#define NBANK 50000
#define NPAD 50048          // 391 * 128
#define KNEI 5
#define ALPHAC 1.0f
#define EPSN 1e-12f
#define NTILES 391          // ceil(50000/128)

typedef short short8 __attribute__((ext_vector_type(8)));
typedef float f32x4 __attribute__((ext_vector_type(4)));

__device__ inline uint32_t f2bf1(float x) {
    union { float f; uint32_t u; } v; v.f = x;
    return (v.u + 0x7FFFu + ((v.u >> 16) & 1u)) >> 16;
}
__device__ inline uint32_t pack2(float a, float b) {
    return f2bf1(a) | (f2bf1(b) << 16);
}
__device__ inline float bl(uint32_t x) {
    union { uint32_t u; float f; } v; v.u = x << 16; return v.f;
}
__device__ inline float bh(uint32_t x) {
    union { uint32_t u; float f; } v; v.u = x & 0xFFFF0000u; return v.f;
}
__device__ inline bool better(float v1, int i1, float v2, int i2) {
    return (v1 > v2) || (v1 == v2 && i1 < i2);
}
__device__ inline void ins6(float v, int j, float* lv, int* li) {
    if (better(v, j, lv[5], li[5])) {
        int q = 5;
        while (q > 0 && better(v, j, lv[q - 1], li[q - 1])) {
            lv[q] = lv[q - 1]; li[q] = li[q - 1]; q--;
        }
        lv[q] = v; li[q] = j;
    }
}
// 256-thread LDS tree merge of per-thread sorted 6-tuples; result in sv/si[0..5]
__device__ inline void tree6(float* sv, int* si, int t, const float* lv, const int* li) {
#pragma unroll
    for (int r = 0; r < 6; r++) { sv[t * 6 + r] = lv[r]; si[t * 6 + r] = li[r]; }
    __syncthreads();
    for (int s = 128; s > 0; s >>= 1) {
        if (t < s) {
            float av[6], bv[6], rv[6];
            int ai[6], bi[6], ri[6];
#pragma unroll
            for (int r = 0; r < 6; r++) {
                av[r] = sv[t * 6 + r];       ai[r] = si[t * 6 + r];
                bv[r] = sv[(t + s) * 6 + r]; bi[r] = si[(t + s) * 6 + r];
            }
            int x = 0, y = 0;
#pragma unroll
            for (int o = 0; o < 6; o++) {
                if (better(av[x], ai[x], bv[y], bi[y])) { rv[o] = av[x]; ri[o] = ai[x]; x++; }
                else                                    { rv[o] = bv[y]; ri[o] = bi[y]; y++; }
            }
#pragma unroll
            for (int r = 0; r < 6; r++) { sv[t * 6 + r] = rv[r]; si[t * 6 + r] = ri[r]; }
        }
        __syncthreads();
    }
}
// async 16B/lane global->LDS
__device__ inline void async16(const void* g, void* l) {
    __builtin_amdgcn_global_load_lds(
        (const __attribute__((address_space(1))) unsigned int*)g,
        (__attribute__((address_space(3))) unsigned int*)l, 16, 0, 0);
}
// tiled+swizzled element offset: 64-col tile `tile`, row r, 8-elem chunk ch
__device__ inline size_t sw_off(int tile, int r, int ch) {
    return (size_t)tile * 8192 + r * 64 + ((ch ^ (r & 7)) * 8);
}

// Kernel 1: zero out; last-write-wins winner flags
__global__ void winner_kernel(const int* __restrict__ trg, int* __restrict__ win,
                              float* __restrict__ out) {
    int t = threadIdx.x;
    if (t == 0) out[0] = 0.f;
    int mv = trg[t];
    int w = 1;
    for (int b2 = t + 1; b2 < BB; b2++)
        if (trg[b2] == mv) w = 0;
    win[t] = w;
}

// Kernel 2: fused row L2-normalize (-> fnb plain + fnb2 swizzled) + row softmax
__global__ void norm_softmax_kernel(const float* __restrict__ feat,
                                    const float* __restrict__ pred,
                                    unsigned short* __restrict__ fnb,
                                    unsigned short* __restrict__ fnb2,
                                    float* __restrict__ p) {
    int b = blockIdx.x, t = threadIdx.x;
    __shared__ float red[256];
    // ---- norm ----
    float x0 = feat[b * DD + t];
    float x1 = feat[b * DD + t + 256];
    red[t] = x0 * x0 + x1 * x1;
    __syncthreads();
    for (int s = 128; s > 0; s >>= 1) {
        if (t < s) red[t] += red[t + s];
        __syncthreads();
    }
    float inv = 1.0f / fmaxf(sqrtf(red[0]), EPSN);
    if (t < 64) {
        const f32x4* src = (const f32x4*)(feat + b * DD + t * 8);
        f32x4 f0 = src[0], f1 = src[1];
        uint4 u = make_uint4(pack2(f0[0] * inv, f0[1] * inv),
                             pack2(f0[2] * inv, f0[3] * inv),
                             pack2(f1[0] * inv, f1[1] * inv),
                             pack2(f1[2] * inv, f1[3] * inv));
        *(uint4*)(fnb + b * DD + t * 8) = u;
        int mtile = b >> 7, r = b & 127, kt = t >> 3, ch = t & 7;
        *(uint4*)(fnb2 + sw_off(mtile * 8 + kt, r, ch)) = u;
    }
    __syncthreads();
    // ---- softmax ----
    float y0 = (t < CC) ? pred[b * CC + t] : -3.0e38f;
    float y1 = (t + 256 < CC) ? pred[b * CC + t + 256] : -3.0e38f;
    red[t] = fmaxf(y0, y1);
    __syncthreads();
    for (int s = 128; s > 0; s >>= 1) {
        if (t < s) red[t] = fmaxf(red[t], red[t + s]);
        __syncthreads();
    }
    float M = red[0];
    __syncthreads();
    float e0 = (t < CC) ? expf(y0 - M) : 0.f;
    float e1 = (t + 256 < CC) ? expf(y1 - M) : 0.f;
    red[t] = e0 + e1;
    __syncthreads();
    for (int s = 128; s > 0; s >>= 1) {
        if (t < s) red[t] += red[t + s];
        __syncthreads();
    }
    float si = 1.0f / red[0];
    if (t < CC) p[b * CC + t] = e0 * si;
    if (t + 256 < CC) p[b * CC + t + 256] = e1 * si;
}

// Kernel 3: bank f32 -> bf16 tiled+swizzled; pad rows zeroed (no repl lookup)
__global__ void convert_kernel(const float* __restrict__ bank,
                               unsigned short* __restrict__ bankb) {
    int tid = blockIdx.x * 256 + threadIdx.x;   // one thread per 8-elem chunk
    int j = tid >> 6, c = tid & 63;
    int kt = c >> 3, ch = c & 7;
    int r = j & 127, nt = j >> 7;
    uint4 val = make_uint4(0, 0, 0, 0);
    if (j < NBANK) {
        const f32x4* s = (const f32x4*)(bank + (size_t)j * DD + kt * 64 + ch * 8);
        f32x4 f0 = s[0], f1 = s[1];
        val = make_uint4(pack2(f0[0], f0[1]), pack2(f0[2], f0[3]),
                         pack2(f1[0], f1[1]), pack2(f1[2], f1[3]));
    }
    *(uint4*)(bankb + sw_off(nt * 8 + kt, r, ch)) = val;
}

// Kernel 4: scatter-patch winner rows: bankb[trg[b]] = fnb[b] (swizzled)
__global__ void patch_kernel(const unsigned short* __restrict__ fnb,
                             const int* __restrict__ trg, const int* __restrict__ win,
                             unsigned short* __restrict__ bankb) {
    int b = blockIdx.x;
    if (!win[b]) return;
    int t = threadIdx.x;   // 64 threads
    int j = trg[b];
    int nt = j >> 7, r = j & 127, kt = t >> 3, ch = t & 7;
    uint4 v = *(const uint4*)(fnb + b * DD + t * 8);
    *(uint4*)(bankb + sw_off(nt * 8 + kt, r, ch)) = v;
}

// Kernel 5: 128x128x512 bf16 MFMA GEMM + branchless per-(row,tile) MAX epilogue
__global__ __launch_bounds__(256) void gemm_topk_kernel(
        const unsigned short* __restrict__ fnb2, const unsigned short* __restrict__ bankb,
        float* __restrict__ tilemax) {
    __shared__ __align__(16) char smem[32768];
    unsigned short* As = (unsigned short*)smem;            // [128][64] 16 KB
    unsigned short* Bs = (unsigned short*)(smem + 16384);  // [128][64] 16 KB

    int t = threadIdx.x;
    int ntb = blockIdx.x >> 1, mtile = blockIdx.x & 1;
    int w = t >> 6, lane = t & 63, quad = lane >> 4, l16 = lane & 15;
    int wm = w >> 1, wn = w & 1;
    int j0 = ntb * 128;

    f32x4 acc[4][4];
#pragma unroll
    for (int mt = 0; mt < 4; mt++)
#pragma unroll
        for (int nt = 0; nt < 4; nt++)
            acc[mt][nt] = (f32x4){0.f, 0.f, 0.f, 0.f};

    const char* Ag = (const char*)fnb2 + (size_t)mtile * 8 * 16384;
    const char* Bg = (const char*)bankb + (size_t)ntb * 8 * 16384;

    for (int kt = 0; kt < 8; kt++) {
        size_t tb = (size_t)kt * 16384;
        int co = w * 4096 + lane * 16;
#pragma unroll
        for (int u = 0; u < 4; u++)
            async16(Ag + tb + co + u * 1024, smem + w * 4096 + u * 1024);
#pragma unroll
        for (int u = 0; u < 4; u++)
            async16(Bg + tb + co + u * 1024, smem + 16384 + w * 4096 + u * 1024);
        __syncthreads();
#pragma unroll
        for (int ks = 0; ks < 2; ks++) {
            int sw = ((ks * 4 + quad) ^ (l16 & 7)) * 8;
            short8 af[4], bf[4];
#pragma unroll
            for (int mt = 0; mt < 4; mt++)
                af[mt] = *(const short8*)(As + (wm * 64 + mt * 16 + l16) * 64 + sw);
#pragma unroll
            for (int nt = 0; nt < 4; nt++)
                bf[nt] = *(const short8*)(Bs + (wn * 64 + nt * 16 + l16) * 64 + sw);
#pragma unroll
            for (int mt = 0; mt < 4; mt++)
#pragma unroll
                for (int nt = 0; nt < 4; nt++)
                    acc[mt][nt] = __builtin_amdgcn_mfma_f32_16x16x32_bf16(
                        af[mt], bf[nt], acc[mt][nt], 0, 0, 0);
        }
        __syncthreads();
    }

    // Branchless epilogue: per-row max over this block's 128 cols.
    bool maskPad[4] = {false, false, false, false};
    if (ntb == NTILES - 1) {
#pragma unroll
        for (int nt = 0; nt < 4; nt++)
            maskPad[nt] = (j0 + wn * 64 + nt * 16 + l16) >= NBANK;
    }
    float* sm = (float*)smem;   // [128][2], aliases dead As
#pragma unroll
    for (int mt = 0; mt < 4; mt++)
#pragma unroll
        for (int r2 = 0; r2 < 4; r2++) {
            float m = -3.4e38f;
#pragma unroll
            for (int nt = 0; nt < 4; nt++) {
                float v = maskPad[nt] ? -3.4e38f : acc[mt][nt][r2];
                m = fmaxf(m, v);
            }
#pragma unroll
            for (int off = 1; off < 16; off <<= 1)
                m = fmaxf(m, __shfl_xor(m, off, 64));
            if (l16 == 0) sm[(wm * 64 + mt * 16 + quad * 4 + r2) * 2 + wn] = m;
        }
    __syncthreads();
    if (t < 128)
        tilemax[(size_t)ntb * 256 + mtile * 128 + t] = fmaxf(sm[t * 2], sm[t * 2 + 1]);
}

// Kernel 6: per row: 6th-largest tile-max threshold -> rescan candidate tiles
// (fp32 recompute from swizzled bf16) -> global top-6 -> ranks 1..5
__global__ void merge_rescan_kernel(const unsigned short* __restrict__ fnb,
                                    const unsigned short* __restrict__ bankb,
                                    const float* __restrict__ tilemax,
                                    int* __restrict__ nidx) {
    int i = blockIdx.x, t = threadIdx.x;
    __shared__ float a[512];
    __shared__ float tm[512];
    __shared__ int cand[NTILES + 1];
    __shared__ int ncand;
    __shared__ float sv[1536];
    __shared__ int si[1536];

    // stage normalized feature row i as f32
    uint32_t wrd = ((const uint32_t*)(fnb + (size_t)i * DD))[t];
    a[2 * t] = bl(wrd);
    a[2 * t + 1] = bh(wrd);
    tm[t] = (t < NTILES) ? tilemax[(size_t)t * 256 + i] : -3.4e38f;
    tm[t + 256] = (t + 256 < NTILES) ? tilemax[(size_t)(t + 256) * 256 + i] : -3.4e38f;
    if (t == 0) ncand = 0;
    __syncthreads();

    // top-6 of the 391 tile maxes (threshold M6)
    float lv[6]; int li[6];
#pragma unroll
    for (int r = 0; r < 6; r++) { lv[r] = -3.4e38f; li[r] = 0x7FFFFFFF; }
    ins6(tm[t], t, lv, li);
    ins6(tm[t + 256], t + 256, lv, li);
    tree6(sv, si, t, lv, li);
    float M6 = sv[5];
    __syncthreads();   // everyone has M6; sv/si free for reuse

    // collect candidate tiles
    if (t < NTILES && tm[t] >= M6) cand[atomicAdd(&ncand, 1)] = t;
    if (t + 256 < NTILES && tm[t + 256] >= M6) cand[atomicAdd(&ncand, 1)] = t + 256;
    __syncthreads();
    int nc = ncand;

    // rescan: fp32 recompute of candidate tiles' distances, two tiles per pass
#pragma unroll
    for (int r = 0; r < 6; r++) { lv[r] = -3.4e38f; li[r] = 0x7FFFFFFF; }
    int r = t & 127;
    int rx = r & 7;
    for (int c0 = 0; c0 < nc; c0 += 2) {
        int slot = c0 + (t >> 7);
        if (slot < nc) {
            int nt = cand[slot];
            int j = nt * 128 + r;
            if (j < NBANK) {
                float dot = 0.f;
#pragma unroll
                for (int kt = 0; kt < 8; kt++) {
                    const uint4* q = (const uint4*)(bankb + (size_t)(nt * 8 + kt) * 8192 + r * 64);
                    const float* ab = a + kt * 64;
#pragma unroll
                    for (int pp = 0; pp < 8; pp++) {
                        uint4 u = q[pp];
                        const float* av = ab + ((pp ^ rx) << 3);
                        dot += bl(u.x) * av[0] + bh(u.x) * av[1]
                             + bl(u.y) * av[2] + bh(u.y) * av[3]
                             + bl(u.z) * av[4] + bh(u.z) * av[5]
                             + bl(u.w) * av[6] + bh(u.w) * av[7];
                    }
                }
                ins6(dot, j, lv, li);
            }
        }
    }
    tree6(sv, si, t, lv, li);
    if (t == 0) {
#pragma unroll
        for (int rr = 1; rr < 6; rr++) nidx[i * KNEI + rr - 1] = si[rr];
    }
}

// Kernel 7: fused KL term (blocks 0..255) + neg_pred columns (blocks 256..600)
__global__ void kl_negpred_kernel(const float* __restrict__ p,
                                  const float* __restrict__ sbank,
                                  const int* __restrict__ nidx,
                                  const int* __restrict__ trg,
                                  float* __restrict__ out) {
    int bid = blockIdx.x, t = threadIdx.x;
    __shared__ float red[256];
    __shared__ float aux[256];
    if (bid < BB) {
        int b = bid;
        __shared__ int sj[KNEI], sb[KNEI];
        if (t < KNEI) {
            int j = nidx[b * KNEI + t];
            sj[t] = j;
            int src = -1;
            for (int b2 = 0; b2 < BB; b2++)
                if (trg[b2] == j) src = b2;   // last wins
            sb[t] = src;
        }
        __syncthreads();
        float local = 0.f;
        for (int k = 0; k < KNEI; k++) {
            int j = sj[k], src = sb[k];
            const float* srow = (src >= 0) ? (p + src * CC) : (sbank + (size_t)j * CC);
            for (int c = t; c < CC; c += 256) {
                float s = srow[c];
                local += s * (logf(s) - p[b * CC + c]);
            }
        }
        red[t] = local;
        __syncthreads();
        for (int s = 128; s > 0; s >>= 1) {
            if (t < s) red[t] += red[t + s];
            __syncthreads();
        }
        if (t == 0) atomicAdd(out, red[0] * (1.0f / BB));
    } else {
        int c = bid - BB;   // 0..CC-1
        float v = p[t * CC + c];
        red[t] = v;
        aux[t] = v * v;
        __syncthreads();
        for (int s = 128; s > 0; s >>= 1) {
            if (t < s) { red[t] += red[t + s]; aux[t] += aux[t + s]; }
            __syncthreads();
        }
        if (t == 0) atomicAdd(out, ALPHAC * (red[0] * red[0] - aux[0]) * (1.0f / BB));
    }
}

extern "C" void kernel_launch(void* const* d_in, const int* in_sizes, int n_in,
                              void* d_out, int out_size, void* d_ws, size_t ws_size,
                              hipStream_t stream) {
    const float* feat  = (const float*)d_in[0];
    const float* pred  = (const float*)d_in[1];
    const float* bank  = (const float*)d_in[2];
    const float* sbank = (const float*)d_in[3];
    const int*   trg   = (const int*)d_in[4];
    float* out = (float*)d_out;

    char* ws = (char*)d_ws;
    unsigned short* fnb2    = (unsigned short*)ws;              //    262,144 B
    unsigned short* fnb     = (unsigned short*)(ws + 262144);   //    262,144 B
    unsigned short* bankb   = (unsigned short*)(ws + 524288);   // 51,249,152 B
    float*          p       = (float*)(ws + 51773440);          //    353,280 B
    int*            win     = (int*)(ws + 52126720);            //      1,024 B
    float*          tilemax = (float*)(ws + 52127744);          //    400,384 B
    int*            nidx    = (int*)(ws + 52528128);            //      5,120 B

    winner_kernel<<<1, 256, 0, stream>>>(trg, win, out);
    norm_softmax_kernel<<<BB, 256, 0, stream>>>(feat, pred, fnb, fnb2, p);
    convert_kernel<<<(NPAD * 64) / 256, 256, 0, stream>>>(bank, bankb);
    patch_kernel<<<BB, 64, 0, stream>>>(fnb, trg, win, bankb);
    gemm_topk_kernel<<<NTILES * 2, 256, 0, stream>>>(fnb2, bankb, tilemax);
    merge_rescan_kernel<<<BB, 256, 0, stream>>>(fnb, bankb, tilemax, nidx);
    kl_negpred_kernel<<<BB + CC, 256, 0, stream>>>(p, sbank, nidx, trg, out);
}

// Round 5
// 284.273 us; speedup vs baseline: 1.3410x; 1.0272x over previous
//
#include <hip/hip_runtime.h>
#include <cstdint>

#define BB 256
#define DD 512
#define CC 345
#define NBANK 50000
#define NPAD 50048          // 391 * 128
#define KNEI 5
#define ALPHAC 1.0f
#define EPSN 1e-12f
#define NTILES 391          // ceil(50000/128)
#define NHALF (NTILES * 2)  // 782 64-col halves
#define CSLOTS (NTILES * 4) // 2 keys per half -> 1564 u64 per row

typedef short short8 __attribute__((ext_vector_type(8)));
typedef float f32x4 __attribute__((ext_vector_type(4)));
typedef unsigned long long u64;

__device__ inline uint32_t f2bf1(float x) {
    union { float f; uint32_t u; } v; v.f = x;
    return (v.u + 0x7FFFu + ((v.u >> 16) & 1u)) >> 16;
}
__device__ inline uint32_t pack2(float a, float b) {
    return f2bf1(a) | (f2bf1(b) << 16);
}
__device__ inline float bl(uint32_t x) {
    union { uint32_t u; float f; } v; v.u = x << 16; return v.f;
}
__device__ inline float bh(uint32_t x) {
    union { uint32_t u; float f; } v; v.u = x & 0xFFFF0000u; return v.f;
}
// packed sort key: high32 = monotone float bits, low32 = ~j  (bigger = better:
// larger value, then smaller index). 0 is a safe "empty" sentinel.
__device__ inline u64 mkkey(float v, int j) {
    union { float f; uint32_t u; } c; c.f = v;
    uint32_t b = c.u;
    uint32_t k = (b & 0x80000000u) ? ~b : (b | 0x80000000u);
    return ((u64)k << 32) | (uint32_t)(~j);
}
__device__ inline u64 umax64(u64 a, u64 b) { return a > b ? a : b; }
__device__ inline u64 shfl_xor_u64(u64 v, int m) {
    int lo = __shfl_xor((int)(uint32_t)v, m, 64);
    int hi = __shfl_xor((int)(v >> 32), m, 64);
    return ((u64)(uint32_t)hi << 32) | (uint32_t)lo;
}
__device__ inline void ins6u(u64 k, u64* lv) {
    if (k > lv[5]) {
        int q = 5;
        while (q > 0 && k > lv[q - 1]) { lv[q] = lv[q - 1]; q--; }
        lv[q] = k;
    }
}
// 256-thread LDS tree merge of per-thread sorted-desc 6-tuples -> sv[0..5]
__device__ inline void tree6u(u64* sv, int t, const u64* lv) {
#pragma unroll
    for (int r = 0; r < 6; r++) sv[t * 6 + r] = lv[r];
    __syncthreads();
    for (int s = 128; s > 0; s >>= 1) {
        if (t < s) {
            u64 av[6], bv[6], rv[6];
#pragma unroll
            for (int r = 0; r < 6; r++) { av[r] = sv[t * 6 + r]; bv[r] = sv[(t + s) * 6 + r]; }
            int x = 0, y = 0;
#pragma unroll
            for (int o = 0; o < 6; o++) {    // x+y==o<=5 so reads stay in range
                bool pk = av[x] > bv[y];
                rv[o] = pk ? av[x] : bv[y];
                x += pk; y += !pk;
            }
#pragma unroll
            for (int r = 0; r < 6; r++) sv[t * 6 + r] = rv[r];
        }
        __syncthreads();
    }
}
// async 16B/lane global->LDS
__device__ inline void async16(const void* g, void* l) {
    __builtin_amdgcn_global_load_lds(
        (const __attribute__((address_space(1))) unsigned int*)g,
        (__attribute__((address_space(3))) unsigned int*)l, 16, 0, 0);
}
// tiled+swizzled element offset: 64-col tile `tile`, row r, 8-elem chunk ch
__device__ inline size_t sw_off(int tile, int r, int ch) {
    return (size_t)tile * 8192 + r * 64 + ((ch ^ (r & 7)) * 8);
}

// Kernel 1: zero out; last-write-wins winner flags (trg staged in LDS)
__global__ void winner_kernel(const int* __restrict__ trg, int* __restrict__ win,
                              float* __restrict__ out) {
    int t = threadIdx.x;
    __shared__ int st[BB];
    if (t == 0) out[0] = 0.f;
    st[t] = trg[t];
    __syncthreads();
    int mv = st[t];
    int w = 1;
    for (int b2 = t + 1; b2 < BB; b2++)
        if (st[b2] == mv) w = 0;
    win[t] = w;
}

// Kernel 2: fused row L2-normalize (-> fnb plain + fnb2 swizzled) + row softmax
__global__ void norm_softmax_kernel(const float* __restrict__ feat,
                                    const float* __restrict__ pred,
                                    unsigned short* __restrict__ fnb,
                                    unsigned short* __restrict__ fnb2,
                                    float* __restrict__ p) {
    int b = blockIdx.x, t = threadIdx.x;
    __shared__ float red[256];
    float x0 = feat[b * DD + t];
    float x1 = feat[b * DD + t + 256];
    red[t] = x0 * x0 + x1 * x1;
    __syncthreads();
    for (int s = 128; s > 0; s >>= 1) {
        if (t < s) red[t] += red[t + s];
        __syncthreads();
    }
    float inv = 1.0f / fmaxf(sqrtf(red[0]), EPSN);
    if (t < 64) {
        const f32x4* src = (const f32x4*)(feat + b * DD + t * 8);
        f32x4 f0 = src[0], f1 = src[1];
        uint4 u = make_uint4(pack2(f0[0] * inv, f0[1] * inv),
                             pack2(f0[2] * inv, f0[3] * inv),
                             pack2(f1[0] * inv, f1[1] * inv),
                             pack2(f1[2] * inv, f1[3] * inv));
        *(uint4*)(fnb + b * DD + t * 8) = u;
        int mtile = b >> 7, r = b & 127, kt = t >> 3, ch = t & 7;
        *(uint4*)(fnb2 + sw_off(mtile * 8 + kt, r, ch)) = u;
    }
    __syncthreads();
    float y0 = (t < CC) ? pred[b * CC + t] : -3.0e38f;
    float y1 = (t + 256 < CC) ? pred[b * CC + t + 256] : -3.0e38f;
    red[t] = fmaxf(y0, y1);
    __syncthreads();
    for (int s = 128; s > 0; s >>= 1) {
        if (t < s) red[t] = fmaxf(red[t], red[t + s]);
        __syncthreads();
    }
    float M = red[0];
    __syncthreads();
    float e0 = (t < CC) ? expf(y0 - M) : 0.f;
    float e1 = (t + 256 < CC) ? expf(y1 - M) : 0.f;
    red[t] = e0 + e1;
    __syncthreads();
    for (int s = 128; s > 0; s >>= 1) {
        if (t < s) red[t] += red[t + s];
        __syncthreads();
    }
    float si = 1.0f / red[0];
    if (t < CC) p[b * CC + t] = e0 * si;
    if (t + 256 < CC) p[b * CC + t + 256] = e1 * si;
}

// Kernel 3: bank f32 -> bf16 tiled+swizzled; pad rows zeroed
__global__ void convert_kernel(const float* __restrict__ bank,
                               unsigned short* __restrict__ bankb) {
    int tid = blockIdx.x * 256 + threadIdx.x;
    int j = tid >> 6, c = tid & 63;
    int kt = c >> 3, ch = c & 7;
    int r = j & 127, nt = j >> 7;
    uint4 val = make_uint4(0, 0, 0, 0);
    if (j < NBANK) {
        const f32x4* s = (const f32x4*)(bank + (size_t)j * DD + kt * 64 + ch * 8);
        f32x4 f0 = s[0], f1 = s[1];
        val = make_uint4(pack2(f0[0], f0[1]), pack2(f0[2], f0[3]),
                         pack2(f1[0], f1[1]), pack2(f1[2], f1[3]));
    }
    *(uint4*)(bankb + sw_off(nt * 8 + kt, r, ch)) = val;
}

// Kernel 4: scatter-patch winner rows: bankb[trg[b]] = fnb[b] (swizzled)
__global__ void patch_kernel(const unsigned short* __restrict__ fnb,
                             const int* __restrict__ trg, const int* __restrict__ win,
                             unsigned short* __restrict__ bankb) {
    int b = blockIdx.x;
    if (!win[b]) return;
    int t = threadIdx.x;   // 64 threads
    int j = trg[b];
    int nt = j >> 7, r = j & 127, kt = t >> 3, ch = t & 7;
    uint4 v = *(const uint4*)(fnb + b * DD + t * 8);
    *(uint4*)(bankb + sw_off(nt * 8 + kt, r, ch)) = v;
}

// Kernel 5: 128x128x512 bf16 MFMA GEMM + branchless per-(row,64-half) top-2 keys
__global__ __launch_bounds__(256) void gemm_topk_kernel(
        const unsigned short* __restrict__ fnb2, const unsigned short* __restrict__ bankb,
        u64* __restrict__ cand) {
    __shared__ __align__(16) char smem[32768];
    unsigned short* As = (unsigned short*)smem;            // [128][64] 16 KB
    unsigned short* Bs = (unsigned short*)(smem + 16384);  // [128][64] 16 KB

    int t = threadIdx.x;
    int ntb = blockIdx.x >> 1, mtile = blockIdx.x & 1;
    int w = t >> 6, lane = t & 63, quad = lane >> 4, l16 = lane & 15;
    int wm = w >> 1, wn = w & 1;
    int j0 = ntb * 128;

    f32x4 acc[4][4];
#pragma unroll
    for (int mt = 0; mt < 4; mt++)
#pragma unroll
        for (int nt = 0; nt < 4; nt++)
            acc[mt][nt] = (f32x4){0.f, 0.f, 0.f, 0.f};

    const char* Ag = (const char*)fnb2 + (size_t)mtile * 8 * 16384;
    const char* Bg = (const char*)bankb + (size_t)ntb * 8 * 16384;

    for (int kt = 0; kt < 8; kt++) {
        size_t tb = (size_t)kt * 16384;
        int co = w * 4096 + lane * 16;
#pragma unroll
        for (int u = 0; u < 4; u++)
            async16(Ag + tb + co + u * 1024, smem + w * 4096 + u * 1024);
#pragma unroll
        for (int u = 0; u < 4; u++)
            async16(Bg + tb + co + u * 1024, smem + 16384 + w * 4096 + u * 1024);
        __syncthreads();
#pragma unroll
        for (int ks = 0; ks < 2; ks++) {
            int sw = ((ks * 4 + quad) ^ (l16 & 7)) * 8;
            short8 af[4], bf[4];
#pragma unroll
            for (int mt = 0; mt < 4; mt++)
                af[mt] = *(const short8*)(As + (wm * 64 + mt * 16 + l16) * 64 + sw);
#pragma unroll
            for (int nt = 0; nt < 4; nt++)
                bf[nt] = *(const short8*)(Bs + (wn * 64 + nt * 16 + l16) * 64 + sw);
#pragma unroll
            for (int mt = 0; mt < 4; mt++)
#pragma unroll
                for (int nt = 0; nt < 4; nt++)
                    acc[mt][nt] = __builtin_amdgcn_mfma_f32_16x16x32_bf16(
                        af[mt], bf[nt], acc[mt][nt], 0, 0, 0);
        }
        __syncthreads();
    }

    // Branchless epilogue: top-2 packed keys per (row, 64-col half)
    bool maskPad[4];
#pragma unroll
    for (int nt = 0; nt < 4; nt++)
        maskPad[nt] = (ntb == NTILES - 1) && ((j0 + wn * 64 + nt * 16 + l16) >= NBANK);

#pragma unroll
    for (int mt = 0; mt < 4; mt++)
#pragma unroll
        for (int r2 = 0; r2 < 4; r2++) {
            u64 k[4];
#pragma unroll
            for (int nt = 0; nt < 4; nt++) {
                int j = j0 + wn * 64 + nt * 16 + l16;
                k[nt] = maskPad[nt] ? 0ull : mkkey(acc[mt][nt][r2], j);
            }
            u64 m = umax64(umax64(k[0], k[1]), umax64(k[2], k[3]));
#pragma unroll
            for (int off = 1; off < 16; off <<= 1)
                m = umax64(m, shfl_xor_u64(m, off));
            u64 top1 = m;
#pragma unroll
            for (int nt = 0; nt < 4; nt++) k[nt] = (k[nt] == top1) ? 0ull : k[nt];
            m = umax64(umax64(k[0], k[1]), umax64(k[2], k[3]));
#pragma unroll
            for (int off = 1; off < 16; off <<= 1)
                m = umax64(m, shfl_xor_u64(m, off));
            if (l16 == 0) {
                int gi = mtile * 128 + wm * 64 + mt * 16 + quad * 4 + r2;
                u64* cp = cand + (size_t)gi * CSLOTS + (ntb * 2 + wn) * 2;
                cp[0] = top1; cp[1] = m;
            }
        }
}

// Kernel 6: per-row merge of 1564 stored keys -> exact top-6 (fallback rescan
// of any half whose stored 2nd >= merged 6th; ~never executes) -> ranks 1..5
__global__ __launch_bounds__(256) void merge_kernel(
        const u64* __restrict__ cand, const unsigned short* __restrict__ fnb,
        const unsigned short* __restrict__ bankb, int* __restrict__ nidx) {
    int i = blockIdx.x, t = threadIdx.x;
    __shared__ u64 sv[1536];
    __shared__ uint32_t fm[25];
    __shared__ int fl[128];
    __shared__ int nf;
    __shared__ float a[512];
    const u64* cr = cand + (size_t)i * CSLOTS;

    u64 lv[6] = {0, 0, 0, 0, 0, 0};
    for (int q = t; q < CSLOTS; q += 256) ins6u(cr[q], lv);
    if (t < 25) fm[t] = 0;
    if (t == 0) nf = 0;
    tree6u(sv, t, lv);
    u64 M6 = sv[5];
    __syncthreads();
    for (int h = t; h < NHALF; h += 256) {
        if (cr[h * 2 + 1] >= M6) {
            int s = atomicAdd(&nf, 1);
            if (s < 128) fl[s] = h;
            atomicOr(&fm[h >> 5], 1u << (h & 31));
        }
    }
    __syncthreads();
    if (nf > 0) {   // exact fallback — probability ~1e-4 per call
        uint32_t wrd = ((const uint32_t*)(fnb + (size_t)i * DD))[t];
        a[2 * t] = bl(wrd);
        a[2 * t + 1] = bh(wrd);
        __syncthreads();
        u64 l2[6] = {0, 0, 0, 0, 0, 0};
        for (int q = t; q < CSLOTS; q += 256) {    // stored keys, unflagged halves
            int h = q >> 1;
            if (!((fm[h >> 5] >> (h & 31)) & 1u)) ins6u(cr[q], l2);
        }
        int nfl = nf < 128 ? nf : 128;
        for (int s = 0; s < nfl; s++) {            // full recompute, flagged halves
            int h = fl[s];
            if (t < 64) {
                int nt2 = h >> 1;
                int r = (h & 1) * 64 + t;
                int j = nt2 * 128 + r;
                if (j < NBANK) {
                    int rx = r & 7;
                    float dot = 0.f;
                    for (int kt = 0; kt < 8; kt++) {
                        const uint4* q4 = (const uint4*)(bankb + (size_t)(nt2 * 8 + kt) * 8192 + r * 64);
                        const float* ab = a + kt * 64;
#pragma unroll
                        for (int pp = 0; pp < 8; pp++) {
                            uint4 u = q4[pp];
                            const float* av = ab + ((pp ^ rx) << 3);
                            dot += bl(u.x) * av[0] + bh(u.x) * av[1]
                                 + bl(u.y) * av[2] + bh(u.y) * av[3]
                                 + bl(u.z) * av[4] + bh(u.z) * av[5]
                                 + bl(u.w) * av[6] + bh(u.w) * av[7];
                        }
                    }
                    ins6u(mkkey(dot, j), l2);
                }
            }
        }
        __syncthreads();
        tree6u(sv, t, l2);
    }
    if (t == 0) {
#pragma unroll
        for (int r = 1; r < 6; r++)
            nidx[i * KNEI + r - 1] = (int)(~(uint32_t)(sv[r] & 0xFFFFFFFFull));
    }
}

// Kernel 7: fused KL term (blocks 0..255) + neg_pred columns (blocks 256..600)
__global__ void kl_negpred_kernel(const float* __restrict__ p,
                                  const float* __restrict__ sbank,
                                  const int* __restrict__ nidx,
                                  const int* __restrict__ trg,
                                  float* __restrict__ out) {
    int bid = blockIdx.x, t = threadIdx.x;
    __shared__ float red[256];
    __shared__ float aux[256];
    if (bid < BB) {
        int b = bid;
        __shared__ int st[BB];
        __shared__ int sj[KNEI], sb[KNEI];
        st[t] = trg[t];
        __syncthreads();
        if (t < KNEI) {
            int j = nidx[b * KNEI + t];
            sj[t] = j;
            int src = -1;
            for (int b2 = 0; b2 < BB; b2++)
                if (st[b2] == j) src = b2;   // last wins
            sb[t] = src;
        }
        __syncthreads();
        float local = 0.f;
        for (int k = 0; k < KNEI; k++) {
            int j = sj[k], src = sb[k];
            const float* srow = (src >= 0) ? (p + src * CC) : (sbank + (size_t)j * CC);
            for (int c = t; c < CC; c += 256) {
                float s = srow[c];
                local += s * (logf(s) - p[b * CC + c]);
            }
        }
        red[t] = local;
        __syncthreads();
        for (int s = 128; s > 0; s >>= 1) {
            if (t < s) red[t] += red[t + s];
            __syncthreads();
        }
        if (t == 0) atomicAdd(out, red[0] * (1.0f / BB));
    } else {
        int c = bid - BB;
        float v = p[t * CC + c];
        red[t] = v;
        aux[t] = v * v;
        __syncthreads();
        for (int s = 128; s > 0; s >>= 1) {
            if (t < s) { red[t] += red[t + s]; aux[t] += aux[t + s]; }
            __syncthreads();
        }
        if (t == 0) atomicAdd(out, ALPHAC * (red[0] * red[0] - aux[0]) * (1.0f / BB));
    }
}

extern "C" void kernel_launch(void* const* d_in, const int* in_sizes, int n_in,
                              void* d_out, int out_size, void* d_ws, size_t ws_size,
                              hipStream_t stream) {
    const float* feat  = (const float*)d_in[0];
    const float* pred  = (const float*)d_in[1];
    const float* bank  = (const float*)d_in[2];
    const float* sbank = (const float*)d_in[3];
    const int*   trg   = (const int*)d_in[4];
    float* out = (float*)d_out;

    char* ws = (char*)d_ws;
    unsigned short* fnb2  = (unsigned short*)ws;              //    262,144 B
    unsigned short* fnb   = (unsigned short*)(ws + 262144);   //    262,144 B
    unsigned short* bankb = (unsigned short*)(ws + 524288);   // 51,249,152 B
    float*          p     = (float*)(ws + 51773440);          //    353,280 B
    int*            win   = (int*)(ws + 52126720);            //      1,024 B
    u64*            cand  = (u64*)(ws + 52127744);            //  3,203,072 B
    int*            nidx  = (int*)(ws + 55330816);            //      5,120 B

    winner_kernel<<<1, 256, 0, stream>>>(trg, win, out);
    norm_softmax_kernel<<<BB, 256, 0, stream>>>(feat, pred, fnb, fnb2, p);
    convert_kernel<<<(NPAD * 64) / 256, 256, 0, stream>>>(bank, bankb);
    patch_kernel<<<BB, 64, 0, stream>>>(fnb, trg, win, bankb);
    gemm_topk_kernel<<<NTILES * 2, 256, 0, stream>>>(fnb2, bankb, cand);
    merge_kernel<<<BB, 256, 0, stream>>>(cand, fnb, bankb, nidx);
    kl_negpred_kernel<<<BB + CC, 256, 0, stream>>>(p, sbank, nidx, trg, out);
}

// Round 6
// 272.333 us; speedup vs baseline: 1.3998x; 1.0438x over previous
//
#include <hip/hip_runtime.h>
#include <cstdint>

#define BB 256
#define DD 512
#define CC 345
#define NBANK 50000
#define NPAD 50048          // 782 * 64
#define KNEI 5
#define ALPHAC 1.0f
#define EPSN 1e-12f
#define NHALF 782           // 64-col tiles = one per block
#define CSLOTS (NHALF * 2)  // 2 keys per tile -> 1564 u64 per row

typedef short short8 __attribute__((ext_vector_type(8)));
typedef float f32x4 __attribute__((ext_vector_type(4)));
typedef unsigned long long u64;

__device__ inline uint32_t f2bf1(float x) {
    union { float f; uint32_t u; } v; v.f = x;
    return (v.u + 0x7FFFu + ((v.u >> 16) & 1u)) >> 16;
}
__device__ inline uint32_t pack2(float a, float b) {
    return f2bf1(a) | (f2bf1(b) << 16);
}
__device__ inline float bl(uint32_t x) {
    union { uint32_t u; float f; } v; v.u = x << 16; return v.f;
}
__device__ inline float bh(uint32_t x) {
    union { uint32_t u; float f; } v; v.u = x & 0xFFFF0000u; return v.f;
}
// packed sort key: high32 = monotone float bits, low32 = ~j (bigger = better)
__device__ inline u64 mkkey(float v, int j) {
    union { float f; uint32_t u; } c; c.f = v;
    uint32_t b = c.u;
    uint32_t k = (b & 0x80000000u) ? ~b : (b | 0x80000000u);
    return ((u64)k << 32) | (uint32_t)(~j);
}
__device__ inline u64 umax64(u64 a, u64 b) { return a > b ? a : b; }
__device__ inline u64 shfl_xor_u64(u64 v, int m) {
    int lo = __shfl_xor((int)(uint32_t)v, m, 64);
    int hi = __shfl_xor((int)(v >> 32), m, 64);
    return ((u64)(uint32_t)hi << 32) | (uint32_t)lo;
}
__device__ inline void ins6u(u64 k, u64* lv) {
    if (k > lv[5]) {
        int q = 5;
        while (q > 0 && k > lv[q - 1]) { lv[q] = lv[q - 1]; q--; }
        lv[q] = k;
    }
}
// 256-thread LDS tree merge of per-thread sorted-desc 6-tuples -> sv[0..5]
__device__ inline void tree6u(u64* sv, int t, const u64* lv) {
#pragma unroll
    for (int r = 0; r < 6; r++) sv[t * 6 + r] = lv[r];
    __syncthreads();
    for (int s = 128; s > 0; s >>= 1) {
        if (t < s) {
            u64 av[6], bv[6], rv[6];
#pragma unroll
            for (int r = 0; r < 6; r++) { av[r] = sv[t * 6 + r]; bv[r] = sv[(t + s) * 6 + r]; }
            int x = 0, y = 0;
#pragma unroll
            for (int o = 0; o < 6; o++) {
                bool pk = av[x] > bv[y];
                rv[o] = pk ? av[x] : bv[y];
                x += pk; y += !pk;
            }
#pragma unroll
            for (int r = 0; r < 6; r++) sv[t * 6 + r] = rv[r];
        }
        __syncthreads();
    }
}
// async 16B/lane global->LDS: gptr per-lane, lptr wave-uniform
__device__ inline void async16(const void* g, void* l) {
    __builtin_amdgcn_global_load_lds(
        (const __attribute__((address_space(1))) unsigned int*)g,
        (__attribute__((address_space(3))) unsigned int*)l, 16, 0, 0);
}
// swizzled tiled offset (elements): 128-row x 64-col tile, row r, 8-el chunk ch
__device__ inline size_t sw_off(int tile, int r, int ch) {
    return (size_t)tile * 8192 + r * 64 + ((ch ^ (r & 7)) * 8);
}

// Kernel 1: repl[j] = -1
__global__ void repl_init_kernel(int* __restrict__ repl) {
    int idx = blockIdx.x * 256 + threadIdx.x;
    if (idx < NPAD) repl[idx] = -1;
}

// Kernel 2: zero out; last-write-wins scatter repl[trg[b]] = b
__global__ void winner_kernel(const int* __restrict__ trg, int* __restrict__ repl,
                              float* __restrict__ out) {
    int t = threadIdx.x;
    __shared__ int st[BB];
    if (t == 0) out[0] = 0.f;
    st[t] = trg[t];
    __syncthreads();
    int mv = st[t];
    int w = 1;
    for (int b2 = t + 1; b2 < BB; b2++)
        if (st[b2] == mv) w = 0;
    if (w) repl[mv] = t;
}

// Kernel 3: fused row L2-normalize (-> fnb plain + fnb2 swizzled) + row softmax
__global__ void norm_softmax_kernel(const float* __restrict__ feat,
                                    const float* __restrict__ pred,
                                    unsigned short* __restrict__ fnb,
                                    unsigned short* __restrict__ fnb2,
                                    float* __restrict__ p) {
    int b = blockIdx.x, t = threadIdx.x;
    __shared__ float red[256];
    float x0 = feat[b * DD + t];
    float x1 = feat[b * DD + t + 256];
    red[t] = x0 * x0 + x1 * x1;
    __syncthreads();
    for (int s = 128; s > 0; s >>= 1) {
        if (t < s) red[t] += red[t + s];
        __syncthreads();
    }
    float inv = 1.0f / fmaxf(sqrtf(red[0]), EPSN);
    if (t < 64) {
        const f32x4* src = (const f32x4*)(feat + b * DD + t * 8);
        f32x4 f0 = src[0], f1 = src[1];
        uint4 u = make_uint4(pack2(f0[0] * inv, f0[1] * inv),
                             pack2(f0[2] * inv, f0[3] * inv),
                             pack2(f1[0] * inv, f1[1] * inv),
                             pack2(f1[2] * inv, f1[3] * inv));
        *(uint4*)(fnb + b * DD + t * 8) = u;
        int mtile = b >> 7, r = b & 127, kt = t >> 3, ch = t & 7;
        *(uint4*)(fnb2 + sw_off(mtile * 8 + kt, r, ch)) = u;
    }
    __syncthreads();
    float y0 = (t < CC) ? pred[b * CC + t] : -3.0e38f;
    float y1 = (t + 256 < CC) ? pred[b * CC + t + 256] : -3.0e38f;
    red[t] = fmaxf(y0, y1);
    __syncthreads();
    for (int s = 128; s > 0; s >>= 1) {
        if (t < s) red[t] = fmaxf(red[t], red[t + s]);
        __syncthreads();
    }
    float M = red[0];
    __syncthreads();
    float e0 = (t < CC) ? expf(y0 - M) : 0.f;
    float e1 = (t + 256 < CC) ? expf(y1 - M) : 0.f;
    red[t] = e0 + e1;
    __syncthreads();
    for (int s = 128; s > 0; s >>= 1) {
        if (t < s) red[t] += red[t + s];
        __syncthreads();
    }
    float si = 1.0f / red[0];
    if (t < CC) p[b * CC + t] = e0 * si;
    if (t + 256 < CC) p[b * CC + t + 256] = e1 * si;
}

// Kernel 4: 256x64x512 bf16 MFMA GEMM with FUSED f32->bf16 bank conversion and
// repl scatter patch in B staging; branchless per-(row,tile) top-2 key epilogue.
// Each block owns 64 bank rows exclusively -> bank is fetched from HBM once.
__global__ __launch_bounds__(256) void gemm_topk_kernel(
        const unsigned short* __restrict__ fnb2, const float* __restrict__ bank,
        const unsigned short* __restrict__ fnb, const int* __restrict__ repl,
        u64* __restrict__ cand) {
    __shared__ __align__(16) char smem[40960];
    unsigned short* As = (unsigned short*)smem;            // [256][64] 32 KB
    unsigned short* Bs = (unsigned short*)(smem + 32768);  // [64][64]   8 KB

    int t = threadIdx.x;
    int ntb = blockIdx.x;          // 0..781
    int j0 = ntb * 64;
    int w = t >> 6, lane = t & 63, quad = lane >> 4, l16 = lane & 15;

    // B staging role: 4 threads per bank row, 16 floats each
    int br = t >> 2, cq = t & 3;
    int bj = j0 + br;
    int rp = (bj < NBANK) ? repl[bj] : -2;   // -2 OOB, -1 bank row, >=0 fnb row

    f32x4 acc[4][4];
#pragma unroll
    for (int mt = 0; mt < 4; mt++)
#pragma unroll
        for (int nt = 0; nt < 4; nt++)
            acc[mt][nt] = (f32x4){0.f, 0.f, 0.f, 0.f};

    const char* fnb2b = (const char*)fnb2;

    for (int kt = 0; kt < 8; kt++) {
        // A: async16 from swizzled fnb2; wave w copies 8 KB (rows w*64..w*64+63)
        const char* asrc = fnb2b + (size_t)((w < 2 ? kt : kt + 8) * 16384 + (w & 1) * 8192);
        char* adst = smem + w * 8192;
#pragma unroll
        for (int u = 0; u < 8; u++)
            async16(asrc + u * 1024 + lane * 16, adst + u * 1024);
        // B: f32 bank -> registers -> bf16 -> swizzled LDS (repl-patched)
        {
            uint4 b0, b1;
            if (rp >= 0) {
                const uint4* s = (const uint4*)(fnb + (size_t)rp * DD + kt * 64 + cq * 16);
                b0 = s[0]; b1 = s[1];
            } else if (rp == -1) {
                const f32x4* s = (const f32x4*)(bank + (size_t)bj * DD + kt * 64 + cq * 16);
                f32x4 f0 = s[0], f1 = s[1], f2 = s[2], f3 = s[3];
                b0 = make_uint4(pack2(f0[0], f0[1]), pack2(f0[2], f0[3]),
                                pack2(f1[0], f1[1]), pack2(f1[2], f1[3]));
                b1 = make_uint4(pack2(f2[0], f2[1]), pack2(f2[2], f2[3]),
                                pack2(f3[0], f3[1]), pack2(f3[2], f3[3]));
            } else {
                b0 = make_uint4(0, 0, 0, 0);
                b1 = make_uint4(0, 0, 0, 0);
            }
            int c0 = cq * 2;
            *(uint4*)(Bs + br * 64 + ((c0 ^ (br & 7)) * 8)) = b0;
            *(uint4*)(Bs + br * 64 + (((c0 + 1) ^ (br & 7)) * 8)) = b1;
        }
        __syncthreads();
#pragma unroll
        for (int ks = 0; ks < 2; ks++) {
            int swz = ((ks * 4 + quad) ^ (l16 & 7)) * 8;
            short8 af[4], bf[4];
#pragma unroll
            for (int mt = 0; mt < 4; mt++)
                af[mt] = *(const short8*)(As + (w * 64 + mt * 16 + l16) * 64 + swz);
#pragma unroll
            for (int nt = 0; nt < 4; nt++)
                bf[nt] = *(const short8*)(Bs + (nt * 16 + l16) * 64 + swz);
#pragma unroll
            for (int mt = 0; mt < 4; mt++)
#pragma unroll
                for (int nt = 0; nt < 4; nt++)
                    acc[mt][nt] = __builtin_amdgcn_mfma_f32_16x16x32_bf16(
                        af[mt], bf[nt], acc[mt][nt], 0, 0, 0);
        }
        __syncthreads();
    }

    // Branchless epilogue: top-2 packed keys per (row, this block's 64 cols)
    bool maskPad[4];
#pragma unroll
    for (int nt = 0; nt < 4; nt++)
        maskPad[nt] = (ntb == NHALF - 1) && ((j0 + nt * 16 + l16) >= NBANK);

#pragma unroll
    for (int mt = 0; mt < 4; mt++)
#pragma unroll
        for (int r2 = 0; r2 < 4; r2++) {
            u64 k[4];
#pragma unroll
            for (int nt = 0; nt < 4; nt++) {
                int j = j0 + nt * 16 + l16;
                k[nt] = maskPad[nt] ? 0ull : mkkey(acc[mt][nt][r2], j);
            }
            u64 m = umax64(umax64(k[0], k[1]), umax64(k[2], k[3]));
#pragma unroll
            for (int off = 1; off < 16; off <<= 1)
                m = umax64(m, shfl_xor_u64(m, off));
            u64 top1 = m;
#pragma unroll
            for (int nt = 0; nt < 4; nt++) k[nt] = (k[nt] == top1) ? 0ull : k[nt];
            m = umax64(umax64(k[0], k[1]), umax64(k[2], k[3]));
#pragma unroll
            for (int off = 1; off < 16; off <<= 1)
                m = umax64(m, shfl_xor_u64(m, off));
            if (l16 == 0) {
                int gi = w * 64 + mt * 16 + quad * 4 + r2;
                u64* cp = cand + (size_t)gi * CSLOTS + ntb * 2;
                cp[0] = top1; cp[1] = m;
            }
        }
}

// Kernel 5: per-row merge of 1564 stored keys -> exact top-6 (fallback rescan
// of any tile whose stored 2nd >= merged 6th; ~never executes) -> ranks 1..5
__global__ __launch_bounds__(256) void merge_kernel(
        const u64* __restrict__ cand, const unsigned short* __restrict__ fnb,
        const float* __restrict__ bank, const int* __restrict__ repl,
        int* __restrict__ nidx) {
    int i = blockIdx.x, t = threadIdx.x;
    __shared__ u64 sv[1536];
    __shared__ uint32_t fm[25];
    __shared__ int fl[128];
    __shared__ int nf;
    __shared__ float a[512];
    const u64* cr = cand + (size_t)i * CSLOTS;

    u64 lv[6] = {0, 0, 0, 0, 0, 0};
    for (int q = t; q < CSLOTS; q += 256) ins6u(cr[q], lv);
    if (t < 25) fm[t] = 0;
    if (t == 0) nf = 0;
    tree6u(sv, t, lv);
    u64 M6 = sv[5];
    __syncthreads();
    for (int h = t; h < NHALF; h += 256) {
        if (cr[h * 2 + 1] >= M6) {
            int s = atomicAdd(&nf, 1);
            if (s < 128) fl[s] = h;
            atomicOr(&fm[h >> 5], 1u << (h & 31));
        }
    }
    __syncthreads();
    if (nf > 0) {   // exact fallback — rare
        uint32_t wrd = ((const uint32_t*)(fnb + (size_t)i * DD))[t];
        a[2 * t] = bl(wrd);
        a[2 * t + 1] = bh(wrd);
        __syncthreads();
        u64 l2[6] = {0, 0, 0, 0, 0, 0};
        for (int q = t; q < CSLOTS; q += 256) {    // stored keys, unflagged tiles
            int h = q >> 1;
            if (!((fm[h >> 5] >> (h & 31)) & 1u)) ins6u(cr[q], l2);
        }
        int nfl = nf < 128 ? nf : 128;
        for (int s = 0; s < nfl; s++) {            // full recompute, flagged tiles
            int h = fl[s];
            if (t < 64) {
                int j = h * 64 + t;
                if (j < NBANK) {
                    int rp = repl[j];
                    float dot = 0.f;
                    if (rp >= 0) {
                        const uint32_t* rw = (const uint32_t*)(fnb + (size_t)rp * DD);
                        for (int kk = 0; kk < 256; kk++) {
                            uint32_t u = rw[kk];
                            dot += bl(u) * a[2 * kk] + bh(u) * a[2 * kk + 1];
                        }
                    } else {
                        const float* rw = bank + (size_t)j * DD;
                        for (int kk = 0; kk < DD; kk++)
                            dot += bl(f2bf1(rw[kk])) * a[kk];
                    }
                    ins6u(mkkey(dot, j), l2);
                }
            }
        }
        __syncthreads();
        tree6u(sv, t, l2);
    }
    if (t == 0) {
#pragma unroll
        for (int r = 1; r < 6; r++)
            nidx[i * KNEI + r - 1] = (int)(~(uint32_t)(sv[r] & 0xFFFFFFFFull));
    }
}

// Kernel 6: fused KL term (blocks 0..255) + neg_pred columns (blocks 256..600)
__global__ void kl_negpred_kernel(const float* __restrict__ p,
                                  const float* __restrict__ sbank,
                                  const int* __restrict__ nidx,
                                  const int* __restrict__ trg,
                                  float* __restrict__ out) {
    int bid = blockIdx.x, t = threadIdx.x;
    __shared__ float red[256];
    __shared__ float aux[256];
    if (bid < BB) {
        int b = bid;
        __shared__ int st[BB];
        __shared__ int sj[KNEI], sb[KNEI];
        st[t] = trg[t];
        __syncthreads();
        if (t < KNEI) {
            int j = nidx[b * KNEI + t];
            sj[t] = j;
            int src = -1;
            for (int b2 = 0; b2 < BB; b2++)
                if (st[b2] == j) src = b2;   // last wins
            sb[t] = src;
        }
        __syncthreads();
        float local = 0.f;
        for (int k = 0; k < KNEI; k++) {
            int j = sj[k], src = sb[k];
            const float* srow = (src >= 0) ? (p + src * CC) : (sbank + (size_t)j * CC);
            for (int c = t; c < CC; c += 256) {
                float s = srow[c];
                local += s * (logf(s) - p[b * CC + c]);
            }
        }
        red[t] = local;
        __syncthreads();
        for (int s = 128; s > 0; s >>= 1) {
            if (t < s) red[t] += red[t + s];
            __syncthreads();
        }
        if (t == 0) atomicAdd(out, red[0] * (1.0f / BB));
    } else {
        int c = bid - BB;
        float v = p[t * CC + c];
        red[t] = v;
        aux[t] = v * v;
        __syncthreads();
        for (int s = 128; s > 0; s >>= 1) {
            if (t < s) { red[t] += red[t + s]; aux[t] += aux[t + s]; }
            __syncthreads();
        }
        if (t == 0) atomicAdd(out, ALPHAC * (red[0] * red[0] - aux[0]) * (1.0f / BB));
    }
}

extern "C" void kernel_launch(void* const* d_in, const int* in_sizes, int n_in,
                              void* d_out, int out_size, void* d_ws, size_t ws_size,
                              hipStream_t stream) {
    const float* feat  = (const float*)d_in[0];
    const float* pred  = (const float*)d_in[1];
    const float* bank  = (const float*)d_in[2];
    const float* sbank = (const float*)d_in[3];
    const int*   trg   = (const int*)d_in[4];
    float* out = (float*)d_out;

    char* ws = (char*)d_ws;
    unsigned short* fnb2 = (unsigned short*)ws;              //   262,144 B
    unsigned short* fnb  = (unsigned short*)(ws + 262144);   //   262,144 B
    float*          p    = (float*)(ws + 524288);            //   353,280 B
    int*            repl = (int*)(ws + 877568);              //   200,192 B
    u64*            cand = (u64*)(ws + 1077760);             // 3,203,072 B
    int*            nidx = (int*)(ws + 4280832);             //     5,120 B

    repl_init_kernel<<<(NPAD + 255) / 256, 256, 0, stream>>>(repl);
    winner_kernel<<<1, 256, 0, stream>>>(trg, repl, out);
    norm_softmax_kernel<<<BB, 256, 0, stream>>>(feat, pred, fnb, fnb2, p);
    gemm_topk_kernel<<<NHALF, 256, 0, stream>>>(fnb2, bank, fnb, repl, cand);
    merge_kernel<<<BB, 256, 0, stream>>>(cand, fnb, bank, repl, nidx);
    kl_negpred_kernel<<<BB + CC, 256, 0, stream>>>(p, sbank, nidx, trg, out);
}